// Round 3
// baseline (192.413 us; speedup 1.0000x reference)
//
#include <hip/hip_runtime.h>
#include <hip/hip_bf16.h>

// SE_loss_w_threshold: h,v (8,16384,128) fp32, N scalar.
// out[0]=mean(Rp), out[1..8]=R_per_user_p, out[9]=sum(R_per_user_p)

constexpr int U_    = 8;
constexpr int B_    = 16384;
constexpr int NT_   = 128;
constexpr int D_    = 64;
constexpr int ROWP_ = 132;           // padded LDS row stride (floats): banks (4i+k)%32 distinct per row
constexpr int NBLK_ = 1024;
constexpr int WPB_  = 4;             // waves per block
constexpr int TW_   = NBLK_ * WPB_;  // 4096 total waves
constexpr int IT_   = B_ / TW_;      // 4 batches per wave
constexpr float T_THRESH = 0.3f;
constexpr float LOG2_10  = 3.3219280948873623f;

__device__ __forceinline__ float waveReduceSum(float v) {
    #pragma unroll
    for (int m = 1; m < 64; m <<= 1) v += __shfl_xor(v, m, 64);
    return v;
}

// gfx950 hardware transcendentals: v_log_f32 is log2, v_exp_f32 is 2^x.
__device__ __forceinline__ float hw_log2(float x) { return __builtin_amdgcn_logf(x); }
__device__ __forceinline__ float hw_exp2(float x) { return __builtin_amdgcn_exp2f(x); }

__global__ __launch_bounds__(256, 4) void se_main(const float* __restrict__ h,
                                                  const float* __restrict__ vv,
                                                  const float* __restrict__ Np,
                                                  float* __restrict__ partial) {
    // Per-wave PRIVATE staging buffers -> no __syncthreads needed in the loop.
    __shared__ float lds[WPB_][2][U_ * ROWP_];
    __shared__ float red_f[WPB_];
    __shared__ float red_R[WPB_][U_];

    const int tid  = threadIdx.x;
    const int wave = tid >> 6;
    const int lane = tid & 63;
    const int ui   = lane >> 3;  // user i (row of A)
    const int uj   = lane & 7;   // user j (col of A)
    const float Nval = Np[0];

    float* hb = lds[wave][0];
    float* vb = lds[wave][1];

    // Each lane stages 4 float4 of h and 4 of v per batch:
    // idx = t*64 + lane, row = idx>>5 (user), c4 = idx&31 (float4 col)
    int srow[4], sc4[4];
    #pragma unroll
    for (int t = 0; t < 4; ++t) {
        const int idx = t * 64 + lane;
        srow[t] = idx >> 5;
        sc4[t]  = idx & 31;
    }

    float lane_sumR = 0.0f;
    float lane_sumf = 0.0f;

    const int gwave = blockIdx.x * WPB_ + wave;

    // ---- prologue: load batch 0 into registers ----
    float4 hreg[4], vreg[4];
    {
        const int b = gwave;
        #pragma unroll
        for (int t = 0; t < 4; ++t) {
            const size_t goff = (size_t)srow[t] * ((size_t)B_ * NT_) + (size_t)b * NT_ + (size_t)sc4[t] * 4;
            hreg[t] = *reinterpret_cast<const float4*>(h  + goff);
            vreg[t] = *reinterpret_cast<const float4*>(vv + goff);
        }
    }

    for (int it = 0; it < IT_; ++it) {
        // ---- ||v||^2 from registers (covers the whole tile across the wave) ----
        float nsq = 0.0f;
        #pragma unroll
        for (int t = 0; t < 4; ++t)
            nsq += vreg[t].x * vreg[t].x + vreg[t].y * vreg[t].y +
                   vreg[t].z * vreg[t].z + vreg[t].w * vreg[t].w;
        const float normsq = waveReduceSum(nsq);

        // ---- spill registers -> private LDS tile ----
        #pragma unroll
        for (int t = 0; t < 4; ++t) {
            *reinterpret_cast<float4*>(&hb[srow[t] * ROWP_ + sc4[t] * 4]) = hreg[t];
            *reinterpret_cast<float4*>(&vb[srow[t] * ROWP_ + sc4[t] * 4]) = vreg[t];
        }

        // ---- prefetch next batch (in flight during the compute below) ----
        const int bn = (it + 1 < IT_) ? (gwave + (it + 1) * TW_) : gwave;
        #pragma unroll
        for (int t = 0; t < 4; ++t) {
            const size_t goff = (size_t)srow[t] * ((size_t)B_ * NT_) + (size_t)bn * NT_ + (size_t)sc4[t] * 4;
            hreg[t] = *reinterpret_cast<const float4*>(h  + goff);
            vreg[t] = *reinterpret_cast<const float4*>(vv + goff);
        }

        // ---- A[i][j] = sum_k h_c[i][k] * conj(v_c[j][k]) ----
        float are = 0.0f, aim = 0.0f;
        const float* hrow = &hb[ui * ROWP_];
        const float* vrow = &vb[uj * ROWP_];
        #pragma unroll
        for (int k = 0; k < D_; k += 4) {
            const float4 hr = *reinterpret_cast<const float4*>(hrow + k);
            const float4 hi = *reinterpret_cast<const float4*>(hrow + D_ + k);
            const float4 vr = *reinterpret_cast<const float4*>(vrow + k);
            const float4 vi = *reinterpret_cast<const float4*>(vrow + D_ + k);
            are += hr.x * vr.x + hi.x * vi.x;
            aim += hi.x * vr.x - hr.x * vi.x;
            are += hr.y * vr.y + hi.y * vi.y;
            aim += hi.y * vr.y - hr.y * vi.y;
            are += hr.z * vr.z + hi.z * vi.z;
            aim += hi.z * vr.z - hr.z * vi.z;
            are += hr.w * vr.w + hi.w * vi.w;
            aim += hi.w * vr.w - hr.w * vi.w;
        }
        const float Iall = are * are + aim * aim;

        // diag |A[i][i]|^2 (lane 9*i) broadcast to whole i-group
        const float diag = __shfl(Iall, ui * 9, 64);
        // row sum over j (low 3 bits of lane)
        float rowsum = Iall;
        rowsum += __shfl_xor(rowsum, 1, 64);
        rowsum += __shfl_xor(rowsum, 2, 64);
        rowsum += __shfl_xor(rowsum, 4, 64);

        const float Ip   = rowsum - diag;                  // interference (unscaled v)
        const float S    = (8.0f / normsq) * diag;         // scale^2 = num_user / ||v||^2
        const float SINR = S / (Ip + Nval);
        const float R    = hw_log2(1.0f + SINR);

        lane_sumR += R;                                            // per-user R (dup x8 per group)
        lane_sumf += hw_exp2((T_THRESH - R) * LOG2_10) - R;        // 10^(T-R) - R
    }

    // ---- block-level reduction (the only cross-wave communication) ----
    const float wf = waveReduceSum(lane_sumf) * 0.125f;  // each user counted 8x
    if (lane == 0) red_f[wave] = wf;
    if (uj == 0)   red_R[wave][ui] = lane_sumR;          // identical across j within group
    __syncthreads();

    if (tid < U_) {
        float s = 0.0f;
        #pragma unroll
        for (int w = 0; w < WPB_; ++w) s += red_R[w][tid];
        partial[blockIdx.x * 9 + 1 + tid] = s;
    } else if (tid == U_) {
        float s = 0.0f;
        #pragma unroll
        for (int w = 0; w < WPB_; ++w) s += red_f[w];
        partial[blockIdx.x * 9] = s;
    }
}

__global__ __launch_bounds__(256) void se_final(const float* __restrict__ partial,
                                                float* __restrict__ out) {
    __shared__ float sums[9];
    if (threadIdx.x < 9) sums[threadIdx.x] = 0.0f;
    __syncthreads();

    float local[9];
    #pragma unroll
    for (int s = 0; s < 9; ++s) local[s] = 0.0f;
    for (int b = threadIdx.x; b < NBLK_; b += 256) {
        #pragma unroll
        for (int s = 0; s < 9; ++s) local[s] += partial[b * 9 + s];
    }
    #pragma unroll
    for (int s = 0; s < 9; ++s) atomicAdd(&sums[s], local[s]);
    __syncthreads();

    if (threadIdx.x == 0) {
        const float inv = 1.0f / (float)B_;
        out[0] = sums[0] * inv;          // mean(Rp)
        float tot = 0.0f;
        #pragma unroll
        for (int i = 0; i < U_; ++i) {
            const float r = sums[1 + i] * inv;
            out[1 + i] = r;              // R_per_user_p
            tot += r;
        }
        out[9] = tot;                    // sum(R_per_user_p)
    }
}

extern "C" void kernel_launch(void* const* d_in, const int* in_sizes, int n_in,
                              void* d_out, int out_size, void* d_ws, size_t ws_size,
                              hipStream_t stream) {
    const float* h  = (const float*)d_in[0];
    const float* v  = (const float*)d_in[1];
    const float* Np = (const float*)d_in[2];
    float* out      = (float*)d_out;
    float* partial  = (float*)d_ws;   // NBLK_*9 floats, fully overwritten each call

    se_main<<<NBLK_, 256, 0, stream>>>(h, v, Np, partial);
    se_final<<<1, 256, 0, stream>>>(partial, out);
}

// Round 4
// 169.378 us; speedup vs baseline: 1.1360x; 1.1360x over previous
//
#include <hip/hip_runtime.h>
#include <hip/hip_bf16.h>

// SE_loss_w_threshold: h,v (8,16384,128) fp32, N scalar.
// out[0]=mean(Rp), out[1..8]=R_per_user_p, out[9]=sum(R_per_user_p)

constexpr int U_    = 8;
constexpr int B_    = 16384;
constexpr int NT_   = 128;
constexpr int D_    = 64;
constexpr int ROWP_ = 132;           // padded LDS row stride (floats): banks (4i+k)%32 distinct per row
constexpr int NBLK_ = 1024;
constexpr int WPB_  = 4;             // waves per block
constexpr int TW_   = NBLK_ * WPB_;  // 4096 total waves
constexpr int IT_   = B_ / TW_;      // 4 batches per wave
constexpr float T_THRESH = 0.3f;
constexpr float LOG2_10  = 3.3219280948873623f;

__device__ __forceinline__ float waveReduceSum(float v) {
    #pragma unroll
    for (int m = 1; m < 64; m <<= 1) v += __shfl_xor(v, m, 64);
    return v;
}

// gfx950 hardware transcendentals: v_log_f32 computes log2(x), v_exp_f32 computes 2^x.
__device__ __forceinline__ float hw_log2(float x) { return __builtin_amdgcn_logf(x); }
__device__ __forceinline__ float hw_exp2(float x) { return __builtin_amdgcn_exp2f(x); }

__global__ __launch_bounds__(256, 4) void se_main(const float* __restrict__ h,
                                                  const float* __restrict__ vv,
                                                  const float* __restrict__ Np,
                                                  float* __restrict__ partial) {
    // Per-wave PRIVATE staging buffers -> no __syncthreads needed in the loop.
    // Waves desynchronize and hide each other's memory latency.
    __shared__ float lds[WPB_][2][U_ * ROWP_];
    __shared__ float red_f[WPB_];
    __shared__ float red_R[WPB_][U_];

    const int tid  = threadIdx.x;
    const int wave = tid >> 6;
    const int lane = tid & 63;
    const int ui   = lane >> 3;  // user i (row of A)
    const int uj   = lane & 7;   // user j (col of A)
    const float Nval = Np[0];

    float* hb = lds[wave][0];
    float* vb = lds[wave][1];

    float lane_sumR = 0.0f;
    float lane_sumf = 0.0f;

    const int gwave = blockIdx.x * WPB_ + wave;

    for (int it = 0; it < IT_; ++it) {
        const int b = gwave + it * TW_;

        // ---- stage h,v rows for batch b into this wave's private LDS tile ----
        // (values are transient: global -> reg -> LDS within the same unrolled
        //  iteration; nothing lives across the loop back-edge => no spills)
        float nsq = 0.0f;
        #pragma unroll
        for (int t = 0; t < 4; ++t) {
            const int idx = t * 64 + lane;
            const int row = idx >> 5;        // user row 0..7
            const int c4  = idx & 31;        // float4 index within row
            const size_t goff = (size_t)row * ((size_t)B_ * NT_) + (size_t)b * NT_ + (size_t)c4 * 4;
            const float4 h4 = *reinterpret_cast<const float4*>(h  + goff);
            const float4 v4 = *reinterpret_cast<const float4*>(vv + goff);
            *reinterpret_cast<float4*>(&hb[row * ROWP_ + c4 * 4]) = h4;
            *reinterpret_cast<float4*>(&vb[row * ROWP_ + c4 * 4]) = v4;
            nsq += v4.x * v4.x + v4.y * v4.y + v4.z * v4.z + v4.w * v4.w;
        }
        const float normsq = waveReduceSum(nsq);   // sum over all (u, nt) of v^2

        // ---- A[i][j] = sum_k h_c[i][k] * conj(v_c[j][k]) ----
        float are = 0.0f, aim = 0.0f;
        const float* hrow = &hb[ui * ROWP_];
        const float* vrow = &vb[uj * ROWP_];
        #pragma unroll
        for (int k = 0; k < D_; k += 4) {
            const float4 hr = *reinterpret_cast<const float4*>(hrow + k);
            const float4 hi = *reinterpret_cast<const float4*>(hrow + D_ + k);
            const float4 vr = *reinterpret_cast<const float4*>(vrow + k);
            const float4 vi = *reinterpret_cast<const float4*>(vrow + D_ + k);
            are += hr.x * vr.x + hi.x * vi.x;
            aim += hi.x * vr.x - hr.x * vi.x;
            are += hr.y * vr.y + hi.y * vi.y;
            aim += hi.y * vr.y - hr.y * vi.y;
            are += hr.z * vr.z + hi.z * vi.z;
            aim += hi.z * vr.z - hr.z * vi.z;
            are += hr.w * vr.w + hi.w * vi.w;
            aim += hi.w * vr.w - hr.w * vi.w;
        }
        const float Iall = are * are + aim * aim;

        // diag |A[i][i]|^2 (lane 9*i) broadcast to whole i-group
        const float diag = __shfl(Iall, ui * 9, 64);
        // row sum over j (low 3 bits of lane)
        float rowsum = Iall;
        rowsum += __shfl_xor(rowsum, 1, 64);
        rowsum += __shfl_xor(rowsum, 2, 64);
        rowsum += __shfl_xor(rowsum, 4, 64);

        const float Ip   = rowsum - diag;                  // interference (unscaled v)
        const float S    = (8.0f / normsq) * diag;         // scale^2 = num_user / ||v||^2
        const float SINR = S / (Ip + Nval);
        const float R    = hw_log2(1.0f + SINR);

        lane_sumR += R;                                            // per-user R (dup x8 per group)
        lane_sumf += hw_exp2((T_THRESH - R) * LOG2_10) - R;        // 10^(T-R) - R
    }

    // ---- block-level reduction (the only cross-wave communication) ----
    const float wf = waveReduceSum(lane_sumf) * 0.125f;  // each user counted 8x
    if (lane == 0) red_f[wave] = wf;
    if (uj == 0)   red_R[wave][ui] = lane_sumR;          // identical across j within group
    __syncthreads();

    if (tid < U_) {
        float s = 0.0f;
        #pragma unroll
        for (int w = 0; w < WPB_; ++w) s += red_R[w][tid];
        partial[blockIdx.x * 9 + 1 + tid] = s;
    } else if (tid == U_) {
        float s = 0.0f;
        #pragma unroll
        for (int w = 0; w < WPB_; ++w) s += red_f[w];
        partial[blockIdx.x * 9] = s;
    }
}

__global__ __launch_bounds__(256) void se_final(const float* __restrict__ partial,
                                                float* __restrict__ out) {
    __shared__ float sums[9];
    if (threadIdx.x < 9) sums[threadIdx.x] = 0.0f;
    __syncthreads();

    float local[9];
    #pragma unroll
    for (int s = 0; s < 9; ++s) local[s] = 0.0f;
    for (int b = threadIdx.x; b < NBLK_; b += 256) {
        #pragma unroll
        for (int s = 0; s < 9; ++s) local[s] += partial[b * 9 + s];
    }
    #pragma unroll
    for (int s = 0; s < 9; ++s) atomicAdd(&sums[s], local[s]);
    __syncthreads();

    if (threadIdx.x == 0) {
        const float inv = 1.0f / (float)B_;
        out[0] = sums[0] * inv;          // mean(Rp)
        float tot = 0.0f;
        #pragma unroll
        for (int i = 0; i < U_; ++i) {
            const float r = sums[1 + i] * inv;
            out[1 + i] = r;              // R_per_user_p
            tot += r;
        }
        out[9] = tot;                    // sum(R_per_user_p)
    }
}

extern "C" void kernel_launch(void* const* d_in, const int* in_sizes, int n_in,
                              void* d_out, int out_size, void* d_ws, size_t ws_size,
                              hipStream_t stream) {
    const float* h  = (const float*)d_in[0];
    const float* v  = (const float*)d_in[1];
    const float* Np = (const float*)d_in[2];
    float* out      = (float*)d_out;
    float* partial  = (float*)d_ws;   // NBLK_*9 floats, fully overwritten each call

    se_main<<<NBLK_, 256, 0, stream>>>(h, v, Np, partial);
    se_final<<<1, 256, 0, stream>>>(partial, out);
}